// Round 6
// baseline (241.736 us; speedup 1.0000x reference)
//
#include <hip/hip_runtime.h>

// Bilinear resample: inputs (B,S,S,C) fp32, offsets (B,S,S,2) fp32 -> out (B,S,S,C)
// B=16, S=128, C=128.
//
// Revision: nontemporal (no-allocate) tap loads. Ledger: XCD swizzle HURT
// (+16us), 2px/thread ILP NEUTRAL, 8-deep register-pinned MLP NEUTRAL, LDS
// tiling 3.5x WORSE (structurally dead at C=128 fp32). No counter shows
// saturation (HBM 29%, VALU 13%, occ 74%). Remaining theory: L1 miss/fill
// path. Tap window per block ~94KB >> 32KB L1 -> ~32K line fills per CU at
// ~4-5cy/fill ~= the observed ~71us with no saturated BW counter. Probe:
// nt-flagged tap loads skip L1 allocation; the modest (~1.4x) L1-level reuse
// moves to L2 which has 100x headroom. Everything else identical to r5.

constexpr int S = 128;
constexpr int CVEC = 32;           // C/4 = 128/4 float4 groups per pixel
constexpr int PIX_PER_BLOCK = 16;  // 8 pixel-groups x 2 pixels each

typedef float f32x4 __attribute__((ext_vector_type(4)));

__device__ __forceinline__ void tap_setup(int pix, int lane_c, float2 off,
                                          int& i00, int& i01, int& i10, int& i11,
                                          float& fy, float& fx)
{
    const int j   = pix & (S - 1);
    const int rem = pix >> 7;          // b*S + i
    const int i   = rem & (S - 1);
    const int b   = rem >> 7;

    float y = fminf(fmaxf((float)i + off.x, 0.0f), (float)(S - 1));
    float x = fminf(fmaxf((float)j + off.y, 0.0f), (float)(S - 1));

    const float y0f = floorf(y);
    const float x0f = floorf(x);
    const int y0 = (int)y0f;
    const int x0 = (int)x0f;
    // ceil == floor+1 whenever frac>0; when frac==0 that tap is weighted by 0,
    // so clamp replaces ceilf exactly (keeps last row/col in bounds).
    const int y1 = min(y0 + 1, S - 1);
    const int x1 = min(x0 + 1, S - 1);
    fy = y - y0f;                      // row fraction  (reference "fx")
    fx = x - x0f;                      // col fraction  (reference "fy")

    const int base = (b * S * S) * CVEC + lane_c;
    const int r0 = base + y0 * (S * CVEC);
    const int r1 = base + y1 * (S * CVEC);
    i00 = r0 + x0 * CVEC;
    i01 = r0 + x1 * CVEC;
    i10 = r1 + x0 * CVEC;
    i11 = r1 + x1 * CVEC;
}

__global__ __launch_bounds__(256) void resample_kernel(
    const float2* __restrict__ offsets2, // (B*S*S) float2
    const f32x4*  __restrict__ inputs4,  // (B, S, S, C/4) as float4
    f32x4*        __restrict__ out4)     // (B, S, S, C/4)
{
    const int tid    = threadIdx.x;
    const int lane_c = tid & 31;       // channel-group index (0..31)
    const int pg     = tid >> 5;       // pixel-group (0..7)
    const int pix0   = blockIdx.x * PIX_PER_BLOCK + pg;
    const int pix1   = pix0 + 8;

    const float2 off0 = offsets2[pix0];
    const float2 off1 = offsets2[pix1];

    int a00, a01, a10, a11; float fy0, fx0;
    int b00, b01, b10, b11; float fy1, fx1;
    tap_setup(pix0, lane_c, off0, a00, a01, a10, a11, fy0, fx0);
    tap_setup(pix1, lane_c, off1, b00, b01, b10, b11, fy1, fx1);

    // Nontemporal tap loads: no L1 allocation. All 8 issued, then pinned
    // live so the loads stay back-to-back in flight.
    f32x4 va00 = __builtin_nontemporal_load(&inputs4[a00]);
    f32x4 va01 = __builtin_nontemporal_load(&inputs4[a01]);
    f32x4 va10 = __builtin_nontemporal_load(&inputs4[a10]);
    f32x4 va11 = __builtin_nontemporal_load(&inputs4[a11]);
    f32x4 vb00 = __builtin_nontemporal_load(&inputs4[b00]);
    f32x4 vb01 = __builtin_nontemporal_load(&inputs4[b01]);
    f32x4 vb10 = __builtin_nontemporal_load(&inputs4[b10]);
    f32x4 vb11 = __builtin_nontemporal_load(&inputs4[b11]);
    asm volatile("" : "+v"(va00), "+v"(va01), "+v"(va10), "+v"(va11),
                      "+v"(vb00), "+v"(vb01), "+v"(vb10), "+v"(vb11));

    // Match reference order: lerp along x (ref "fy"), then along y (ref "fx").
    const f32x4 vt0 = va00 + (va01 - va00) * fx0;
    const f32x4 vb0 = va10 + (va11 - va10) * fx0;
    const f32x4 o0  = vt0 + (vb0 - vt0) * fy0;
    const f32x4 vt1 = vb00 + (vb01 - vb00) * fx1;
    const f32x4 vb1 = vb10 + (vb11 - vb10) * fx1;
    const f32x4 o1  = vt1 + (vb1 - vt1) * fy1;

    __builtin_nontemporal_store(o0, &out4[(long long)pix0 * CVEC + lane_c]);
    __builtin_nontemporal_store(o1, &out4[(long long)pix1 * CVEC + lane_c]);
}

extern "C" void kernel_launch(void* const* d_in, const int* in_sizes, int n_in,
                              void* d_out, int out_size, void* d_ws, size_t ws_size,
                              hipStream_t stream) {
    const float2* offsets2 = (const float2*)d_in[0];
    const f32x4*  inputs4  = (const f32x4*)d_in[1];
    f32x4*        out4     = (f32x4*)d_out;

    const int B = in_sizes[0] / (S * S * 2);       // = 16
    const int total_pix = B * S * S;               // 262144
    const int blocks = total_pix / PIX_PER_BLOCK;  // 16384

    resample_kernel<<<blocks, 256, 0, stream>>>(offsets2, inputs4, out4);
}

// Round 8
// 236.871 us; speedup vs baseline: 1.0205x; 1.0205x over previous
//
#include <hip/hip_runtime.h>

// Bilinear resample: inputs (B,S,S,C) fp32, offsets (B,S,S,2) fp32 -> out (B,S,S,C)
// B=16, S=128, C=128.
//
// Revision (re-run; round-7 bench was a container infra failure, not a
// kernel failure): persistent software-pipelined gather. Ledger at ~71us
// kernel (roofline 39us): XCD swizzle HURT, burst ILP NEUTRAL x2, LDS tile
// 3.5x HURT, nt tap loads HURT. No pipe saturated. Remaining untested
// hypothesis: burst-and-die waves pay full gather latency once per pixel of
// work; a pipelined persistent thread sustains in-flight loads continuously.
// Each thread: 8 pixels; offsets prefetched 2 iters ahead, taps issued 1
// iter ahead (pinned live via asm), compute overlaps next iter's loads.
// Tap loads are normal (cached) loads; stores stay nontemporal.
// If this is neutral too, the kernel is at the L3/fabric gather ceiling
// (~9 TB/s on 640 MB structural traffic) and that is the roofline.

constexpr int S = 128;
constexpr int CVEC = 32;            // C/4 float4 groups per pixel
constexpr int ITERS = 8;            // pixels per thread(-group)
constexpr int PIX_PER_BLOCK = 8 * ITERS;  // 8 pixel-groups x ITERS

typedef float f32x4 __attribute__((ext_vector_type(4)));

__device__ __forceinline__ void tap_setup(int pix, int lane_c, float2 off,
                                          int& i00, int& i01, int& i10, int& i11,
                                          float& fy, float& fx)
{
    const int j   = pix & (S - 1);
    const int rem = pix >> 7;          // b*S + i
    const int i   = rem & (S - 1);
    const int b   = rem >> 7;

    float y = fminf(fmaxf((float)i + off.x, 0.0f), (float)(S - 1));
    float x = fminf(fmaxf((float)j + off.y, 0.0f), (float)(S - 1));

    const float y0f = floorf(y);
    const float x0f = floorf(x);
    const int y0 = (int)y0f;
    const int x0 = (int)x0f;
    // ceil == floor+1 whenever frac>0; frac==0 taps carry weight 0 -> clamp
    // replaces ceilf exactly (keeps last row/col in bounds).
    const int y1 = min(y0 + 1, S - 1);
    const int x1 = min(x0 + 1, S - 1);
    fy = y - y0f;                      // row fraction  (reference "fx")
    fx = x - x0f;                      // col fraction  (reference "fy")

    const int base = (b * S * S) * CVEC + lane_c;
    const int r0 = base + y0 * (S * CVEC);
    const int r1 = base + y1 * (S * CVEC);
    i00 = r0 + x0 * CVEC;
    i01 = r0 + x1 * CVEC;
    i10 = r1 + x0 * CVEC;
    i11 = r1 + x1 * CVEC;
}

__global__ __launch_bounds__(256) void resample_kernel(
    const float2* __restrict__ offsets2, // (B*S*S) float2
    const f32x4*  __restrict__ inputs4,  // (B, S, S, C/4) as float4
    f32x4*        __restrict__ out4)     // (B, S, S, C/4)
{
    const int tid    = threadIdx.x;
    const int lane_c = tid & 31;
    const int pg     = tid >> 5;
    const int p0     = blockIdx.x * PIX_PER_BLOCK + pg;

    // Prologue: offsets for iter 0 and 1 issued back-to-back, then iter-0
    // taps issued.
    float2 offA = offsets2[p0];
    float2 offB = offsets2[p0 + 8];

    int a00, a01, a10, a11; float fyA, fxA;
    tap_setup(p0, lane_c, offA, a00, a01, a10, a11, fyA, fxA);
    f32x4 v00 = inputs4[a00];
    f32x4 v01 = inputs4[a01];
    f32x4 v10 = inputs4[a10];
    f32x4 v11 = inputs4[a11];

    #pragma unroll
    for (int it = 0; it < ITERS; ++it) {
        const int pix = p0 + it * 8;

        // Prefetch offsets 2 iterations ahead (hides offset->tap round trip).
        float2 offC = offB;
        if (it + 2 < ITERS) offC = offsets2[p0 + (it + 2) * 8];

        // Issue next iteration's taps (depends only on offB, already arrived
        // or in flight since last iteration).
        f32x4 w00, w01, w10, w11;
        float fyB = 0.f, fxB = 0.f;
        if (it + 1 < ITERS) {
            int b00, b01, b10, b11;
            tap_setup(p0 + (it + 1) * 8, lane_c, offB,
                      b00, b01, b10, b11, fyB, fxB);
            w00 = inputs4[b00];
            w01 = inputs4[b01];
            w10 = inputs4[b10];
            w11 = inputs4[b11];
            // Pin: next-iter taps must be live (in flight) before current
            // compute, so the scheduler can't sink them below the store.
            asm volatile("" : "+v"(w00), "+v"(w01), "+v"(w10), "+v"(w11));
        }

        // Compute current pixel (waits only on v-regs).
        const f32x4 vt = v00 + (v01 - v00) * fxA;
        const f32x4 vb = v10 + (v11 - v10) * fxA;
        const f32x4 o  = vt + (vb - vt) * fyA;
        __builtin_nontemporal_store(o, &out4[(long long)pix * CVEC + lane_c]);

        // Rotate pipeline registers.
        if (it + 1 < ITERS) {
            v00 = w00; v01 = w01; v10 = w10; v11 = w11;
            fyA = fyB; fxA = fxB;
            offB = offC;
        }
    }
}

extern "C" void kernel_launch(void* const* d_in, const int* in_sizes, int n_in,
                              void* d_out, int out_size, void* d_ws, size_t ws_size,
                              hipStream_t stream) {
    const float2* offsets2 = (const float2*)d_in[0];
    const f32x4*  inputs4  = (const f32x4*)d_in[1];
    f32x4*        out4     = (f32x4*)d_out;

    const int B = in_sizes[0] / (S * S * 2);       // = 16
    const int total_pix = B * S * S;               // 262144
    const int blocks = total_pix / PIX_PER_BLOCK;  // 4096

    resample_kernel<<<blocks, 256, 0, stream>>>(offsets2, inputs4, out4);
}